// Round 3
// baseline (433.574 us; speedup 1.0000x reference)
//
#include <hip/hip_runtime.h>
#include <stdint.h>

// TopoSignature via parallel Boruvka MST. Round 3: scan_k restructured for
// memory-level parallelism — 2 rows/block (one row per wave-pair), batched
// float4 loads, 8 blocks/CU occupancy (__launch_bounds__(256,8), ~50 VGPRs).

#define N        4096
#define NROUNDS  12
#define SCAN_RPB 2                    // rows per block
#define SCAN_BPM (N / SCAN_RPB)       // 2048 blocks per matrix

typedef unsigned long long u64;
typedef uint32_t u32;

struct Ws {
    u64 best[2][N];     // per-component min outgoing edge key: (wbits<<24)|(lo<<12)|hi
    u32 comp[2][N];     // vertex -> component root label
    u32 edges[2][N];    // recorded MST edges, (lo<<12)|hi
    u32 ecnt[2];
    u32 ncomp[2];
};

__device__ __forceinline__ u64 shfl_down_u64(u64 x, int off) {
    u32 lo = (u32)x, hi = (u32)(x >> 32);
    lo = (u32)__shfl_down((int)lo, off, 64);
    hi = (u32)__shfl_down((int)hi, off, 64);
    return ((u64)hi << 32) | lo;
}

__global__ void init_k(Ws* __restrict__ ws) {
    int i = blockIdx.x * blockDim.x + threadIdx.x;
    if (i < N) {
        ws->best[0][i] = ~0ull; ws->best[1][i] = ~0ull;
        ws->comp[0][i] = (u32)i; ws->comp[1][i] = (u32)i;
        if (i < 2) { ws->ecnt[i] = 0u; ws->ncomp[i] = (u32)N; }
    }
}

// Min outgoing edge per row -> atomicMin into best[comp[row]].
// 256 threads = 4 waves; waves (0,1) cover row b*2+0, waves (2,3) row b*2+1.
// Each lane: 8 batched float4 loads (stride 128 float4s), LDS comp compare.
__launch_bounds__(256, 8)
__global__ void scan_k(const float* __restrict__ d1, const float* __restrict__ d2,
                       Ws* __restrict__ ws) {
    const int m = blockIdx.x / SCAN_BPM;
    const int b = blockIdx.x % SCAN_BPM;
    if (ws->ncomp[m] <= 1u) return;          // uniform per block
    const float* __restrict__ dm = m ? d2 : d1;

    __shared__ u32 compLDS[N];               // 16 KB
    const int tid = threadIdx.x;
    {
        uint4* dst = (uint4*)compLDS;
        const uint4* src = (const uint4*)ws->comp[m];
        for (int k = tid; k < N / 4; k += 256) dst[k] = src[k];
    }
    __syncthreads();

    const int wave = tid >> 6, lane = tid & 63;
    const int v    = b * SCAN_RPB + (wave >> 1);
    const int half = wave & 1;
    const u32 cv   = compLDS[v];
    const float4* __restrict__ row4 = (const float4*)(dm + (size_t)v * N);
    const int base = half * 64 + lane;       // float4 column index; stride 128

    // batch all 8 global loads -> 8 outstanding per lane
    float4 w[8];
    #pragma unroll
    for (int i = 0; i < 8; ++i) w[i] = row4[base + 128 * i];

    // per-row key: (wbits<<32)|col — within a fixed row the global order
    // (w, lo, hi) reduces to (w, col).
    const uint4* c4 = (const uint4*)compLDS;
    u64 kmin = ~0ull;
    #pragma unroll
    for (int i = 0; i < 8; ++i) {
        int c = base + 128 * i;
        uint4 cu = c4[c];
        u32 u0 = (u32)(4 * c);
        if (cu.x != cv) { u64 k = ((u64)__float_as_uint(w[i].x) << 32) | (u0 + 0); if (k < kmin) kmin = k; }
        if (cu.y != cv) { u64 k = ((u64)__float_as_uint(w[i].y) << 32) | (u0 + 1); if (k < kmin) kmin = k; }
        if (cu.z != cv) { u64 k = ((u64)__float_as_uint(w[i].z) << 32) | (u0 + 2); if (k < kmin) kmin = k; }
        if (cu.w != cv) { u64 k = ((u64)__float_as_uint(w[i].w) << 32) | (u0 + 3); if (k < kmin) kmin = k; }
    }
    #pragma unroll
    for (int off = 32; off >= 1; off >>= 1) {
        u64 o = shfl_down_u64(kmin, off);
        if (o < kmin) kmin = o;
    }
    if (lane == 0 && kmin != ~0ull) {
        u32 wb = (u32)(kmin >> 32);
        u32 u  = (u32)kmin & 0xFFFu;
        u32 lo = min((u32)v, u), hi = max((u32)v, u);
        u64 g = ((u64)wb << 24) | ((u64)lo << 12) | (u64)hi;
        atomicMin(&ws->best[m][cv], g);
    }
}

// Hook roots along min edges, resolve 2-cycles, record edges, pointer-jump,
// relabel comp, reset best, update ncomp. One block per matrix.
__launch_bounds__(256, 1)
__global__ void hook_k(Ws* __restrict__ ws) {
    const int m = blockIdx.x;
    const int tid = threadIdx.x;
    if (ws->ncomp[m] <= 1u) return;

    u32* __restrict__ gcomp = ws->comp[m];
    u64* __restrict__ best  = ws->best[m];

    __shared__ u32 compL[N];
    __shared__ u32 nxtA[N];
    __shared__ u32 nxtB[N];
    __shared__ u32 red[4];

    {
        uint4* dst = (uint4*)compL;
        const uint4* src = (const uint4*)gcomp;
        for (int k = tid; k < N / 4; k += 256) dst[k] = src[k];
    }
    __syncthreads();

    bool isroot[16];
    u64  bkey[16];

    // A: each root hooks toward the other endpoint's component
    #pragma unroll
    for (int k = 0; k < 16; ++k) {
        int i = tid + k * 256;
        u32 x = (u32)i;
        bool r = (compL[i] == (u32)i);
        isroot[k] = r;
        u64 g = 0;
        if (r) {
            g = best[i];
            u32 lo = (u32)(g >> 12) & 0xFFFu;
            u32 hi = (u32)g & 0xFFFu;
            u32 cl = compL[lo], ch = compL[hi];
            x = (cl == (u32)i) ? ch : cl;
        }
        bkey[k] = g;
        nxtA[i] = x;
    }
    __syncthreads();

    // B: only 2-cycles possible (strict total order); smaller id becomes root.
    #pragma unroll
    for (int k = 0; k < 16; ++k) {
        int i = tid + k * 256;
        u32 nn = (u32)i;
        if (isroot[k]) {
            u32 o = nxtA[i];
            bool mutual = (nxtA[o] == (u32)i);
            nn = (mutual && ((u32)i < o)) ? (u32)i : o;
            if (nn != (u32)i) {
                u32 pos = atomicAdd(&ws->ecnt[m], 1u);
                if (pos < (u32)N) ws->edges[m][pos] = (u32)(bkey[k] & 0xFFFFFFu);
            }
        }
        nxtB[i] = nn;
    }
    __syncthreads();

    // C: pointer jumping
    for (int s = 0; s < 12; ++s) {
        #pragma unroll
        for (int k = 0; k < 16; ++k) {
            int i = tid + k * 256;
            nxtB[i] = nxtB[nxtB[i]];
        }
        __syncthreads();
    }

    // D: count surviving roots
    u32 cnt = 0;
    #pragma unroll
    for (int k = 0; k < 16; ++k) {
        int i = tid + k * 256;
        if (isroot[k] && nxtB[i] == (u32)i) cnt++;
    }
    #pragma unroll
    for (int off = 32; off >= 1; off >>= 1) cnt += (u32)__shfl_down((int)cnt, off, 64);
    const int lane = tid & 63, wave = tid >> 6;
    if (lane == 0) red[wave] = cnt;
    __syncthreads();

    // E: relabel comp (global), reset best cells of old roots
    #pragma unroll
    for (int k = 0; k < 16; ++k) {
        int i = tid + k * 256;
        gcomp[i] = nxtB[compL[i]];
        if (isroot[k]) best[i] = ~0ull;
    }
    if (tid == 0) ws->ncomp[m] = red[0] + red[1] + red[2] + red[3];
}

__launch_bounds__(256, 1)
__global__ void epi_k(const float* __restrict__ d1, const float* __restrict__ d2,
                      Ws* __restrict__ ws, float* __restrict__ out) {
    const int m = blockIdx.x, tid = threadIdx.x;
    u32 cnt = ws->ecnt[m];
    if (cnt > (u32)N) cnt = (u32)N;
    float acc = 0.f;
    for (u32 i = (u32)tid; i < cnt; i += 256u) {
        u32 pk = ws->edges[m][i];
        u32 lo = (pk >> 12) & 0xFFFu, hi = pk & 0xFFFu;
        size_t off = (size_t)lo * N + hi;
        float df = d1[off] - d2[off];
        acc += df * df;
    }
    #pragma unroll
    for (int off = 32; off >= 1; off >>= 1) acc += __shfl_down(acc, off, 64);
    __shared__ float part[4];
    const int lane = tid & 63, wave = tid >> 6;
    if (lane == 0) part[wave] = acc;
    __syncthreads();
    if (tid == 0) atomicAdd(out, part[0] + part[1] + part[2] + part[3]);
}

extern "C" void kernel_launch(void* const* d_in, const int* in_sizes, int n_in,
                              void* d_out, int out_size, void* d_ws, size_t ws_size,
                              hipStream_t stream) {
    (void)in_sizes; (void)n_in; (void)out_size; (void)ws_size;
    const float* d1 = (const float*)d_in[0];
    const float* d2 = (const float*)d_in[1];
    float* out = (float*)d_out;
    Ws* ws = (Ws*)d_ws;   // ~208 KB of scratch

    hipMemsetAsync(d_out, 0, sizeof(float), stream);
    init_k<<<dim3(16), dim3(256), 0, stream>>>(ws);
    for (int r = 0; r < NROUNDS; ++r) {
        scan_k<<<dim3(2 * SCAN_BPM), dim3(256), 0, stream>>>(d1, d2, ws);
        hook_k<<<dim3(2), dim3(256), 0, stream>>>(ws);
    }
    epi_k<<<dim3(2), dim3(256), 0, stream>>>(d1, d2, ws, out);
}

// Round 4
// 358.307 us; speedup vs baseline: 1.2101x; 1.2101x over previous
//
#include <hip/hip_runtime.h>
#include <stdint.h>

// TopoSignature via parallel Boruvka MST. Round 4: scan_k = one wave per row,
// zero prologue (comp read straight from global, L1/L2-hot), 4 batches of
// 4x(float4+uint4) loads, 32 waves/CU. Round-1 specialized: no comp loads,
// plain store instead of atomic. Later rounds: read-check before atomicMin.

#define N        4096
#define NROUNDS  12

typedef unsigned long long u64;
typedef uint32_t u32;

struct Ws {
    u64 best[2][N];     // per-component min outgoing edge key: (wbits<<24)|(lo<<12)|hi
    u32 comp[2][N];     // vertex -> component root label
    u32 edges[2][N];    // recorded MST edges, (lo<<12)|hi
    u32 ecnt[2];
    u32 ncomp[2];
};

__device__ __forceinline__ u64 shfl_down_u64(u64 x, int off) {
    u32 lo = (u32)x, hi = (u32)(x >> 32);
    lo = (u32)__shfl_down((int)lo, off, 64);
    hi = (u32)__shfl_down((int)hi, off, 64);
    return ((u64)hi << 32) | lo;
}

__global__ void init_k(Ws* __restrict__ ws) {
    int i = blockIdx.x * blockDim.x + threadIdx.x;
    if (i < N) {
        ws->best[0][i] = ~0ull; ws->best[1][i] = ~0ull;
        ws->comp[0][i] = (u32)i; ws->comp[1][i] = (u32)i;
        if (i < 2) { ws->ecnt[i] = 0u; ws->ncomp[i] = (u32)N; }
    }
}

// One wave per row. Blocks 0..1023: matrix 0; 1024..2047: matrix 1.
// Row v = (blockIdx&1023)*4 + wave.
__launch_bounds__(256, 8)
__global__ void scan_k(const float* __restrict__ d1, const float* __restrict__ d2,
                       Ws* __restrict__ ws, int first) {
    const int m = blockIdx.x >> 10;
    if (ws->ncomp[m] <= 1u) return;              // uniform per block
    const int wave = threadIdx.x >> 6, lane = threadIdx.x & 63;
    const int v = ((blockIdx.x & 1023) << 2) + wave;

    const float* __restrict__ dm = m ? d2 : d1;
    const u32*   __restrict__ cm = ws->comp[m];
    const float4* __restrict__ row4 = (const float4*)(dm + (size_t)v * N);
    const uint4*  __restrict__ c4   = (const uint4*)cm;
    const u32 cv = first ? (u32)v : cm[v];

    float wmin = __int_as_float(0x7F800000);     // +inf
    u32   colmin = 0u;

    #pragma unroll
    for (int bb = 0; bb < 4; ++bb) {
        float4 w[4];
        uint4  cu[4];
        #pragma unroll
        for (int i = 0; i < 4; ++i) {
            const int c = lane + 64 * (bb * 4 + i);
            w[i] = row4[c];
            if (!first) cu[i] = c4[c];
        }
        #pragma unroll
        for (int i = 0; i < 4; ++i) {
            const u32 c0 = (u32)(4 * (lane + 64 * (bb * 4 + i)));
            if (first) {
                const u32 uv = (u32)v;
                if (c0+0 != uv && w[i].x < wmin) { wmin = w[i].x; colmin = c0+0; }
                if (c0+1 != uv && w[i].y < wmin) { wmin = w[i].y; colmin = c0+1; }
                if (c0+2 != uv && w[i].z < wmin) { wmin = w[i].z; colmin = c0+2; }
                if (c0+3 != uv && w[i].w < wmin) { wmin = w[i].w; colmin = c0+3; }
            } else {
                if (cu[i].x != cv && w[i].x < wmin) { wmin = w[i].x; colmin = c0+0; }
                if (cu[i].y != cv && w[i].y < wmin) { wmin = w[i].y; colmin = c0+1; }
                if (cu[i].z != cv && w[i].z < wmin) { wmin = w[i].z; colmin = c0+2; }
                if (cu[i].w != cv && w[i].w < wmin) { wmin = w[i].w; colmin = c0+3; }
            }
        }
    }

    // lexicographic (weight, col) wave reduce — strict '<' keeps lowest col on ties
    u64 kmin = ((u64)__float_as_uint(wmin) << 32) | (u64)colmin;
    #pragma unroll
    for (int off = 32; off >= 1; off >>= 1) {
        u64 o = shfl_down_u64(kmin, off);
        if (o < kmin) kmin = o;
    }
    if (lane == 0) {
        u32 wb = (u32)(kmin >> 32);
        u32 u  = (u32)kmin & 0xFFFu;
        u32 lo = min((u32)v, u), hi = max((u32)v, u);
        u64 g  = ((u64)wb << 24) | ((u64)lo << 12) | (u64)hi;
        if (first) {
            ws->best[m][v] = g;                  // comp==v, unique -> plain store
        } else {
            if (g < ws->best[m][cv])             // read-check kills atomic serialization
                atomicMin(&ws->best[m][cv], g);
        }
    }
}

// Hook roots along min edges, resolve 2-cycles, record edges, pointer-jump,
// relabel comp, reset best, update ncomp. One block per matrix.
__launch_bounds__(256, 1)
__global__ void hook_k(Ws* __restrict__ ws) {
    const int m = blockIdx.x;
    const int tid = threadIdx.x;
    if (ws->ncomp[m] <= 1u) return;

    u32* __restrict__ gcomp = ws->comp[m];
    u64* __restrict__ best  = ws->best[m];

    __shared__ u32 compL[N];
    __shared__ u32 nxtA[N];
    __shared__ u32 nxtB[N];
    __shared__ u32 red[4];

    {
        uint4* dst = (uint4*)compL;
        const uint4* src = (const uint4*)gcomp;
        for (int k = tid; k < N / 4; k += 256) dst[k] = src[k];
    }
    __syncthreads();

    bool isroot[16];
    u64  bkey[16];

    // A: each root hooks toward the other endpoint's component
    #pragma unroll
    for (int k = 0; k < 16; ++k) {
        int i = tid + k * 256;
        u32 x = (u32)i;
        bool r = (compL[i] == (u32)i);
        isroot[k] = r;
        u64 g = 0;
        if (r) {
            g = best[i];
            u32 lo = (u32)(g >> 12) & 0xFFFu;
            u32 hi = (u32)g & 0xFFFu;
            u32 cl = compL[lo], ch = compL[hi];
            x = (cl == (u32)i) ? ch : cl;
        }
        bkey[k] = g;
        nxtA[i] = x;
    }
    __syncthreads();

    // B: only 2-cycles possible (strict total order); smaller id becomes root.
    #pragma unroll
    for (int k = 0; k < 16; ++k) {
        int i = tid + k * 256;
        u32 nn = (u32)i;
        if (isroot[k]) {
            u32 o = nxtA[i];
            bool mutual = (nxtA[o] == (u32)i);
            nn = (mutual && ((u32)i < o)) ? (u32)i : o;
            if (nn != (u32)i) {
                u32 pos = atomicAdd(&ws->ecnt[m], 1u);
                if (pos < (u32)N) ws->edges[m][pos] = (u32)(bkey[k] & 0xFFFFFFu);
            }
        }
        nxtB[i] = nn;
    }
    __syncthreads();

    // C: pointer jumping
    for (int s = 0; s < 12; ++s) {
        #pragma unroll
        for (int k = 0; k < 16; ++k) {
            int i = tid + k * 256;
            nxtB[i] = nxtB[nxtB[i]];
        }
        __syncthreads();
    }

    // D: count surviving roots
    u32 cnt = 0;
    #pragma unroll
    for (int k = 0; k < 16; ++k) {
        int i = tid + k * 256;
        if (isroot[k] && nxtB[i] == (u32)i) cnt++;
    }
    #pragma unroll
    for (int off = 32; off >= 1; off >>= 1) cnt += (u32)__shfl_down((int)cnt, off, 64);
    const int lane = tid & 63, wave = tid >> 6;
    if (lane == 0) red[wave] = cnt;
    __syncthreads();

    // E: relabel comp (global), reset best cells of old roots
    #pragma unroll
    for (int k = 0; k < 16; ++k) {
        int i = tid + k * 256;
        gcomp[i] = nxtB[compL[i]];
        if (isroot[k]) best[i] = ~0ull;
    }
    if (tid == 0) ws->ncomp[m] = red[0] + red[1] + red[2] + red[3];
}

__launch_bounds__(256, 1)
__global__ void epi_k(const float* __restrict__ d1, const float* __restrict__ d2,
                      Ws* __restrict__ ws, float* __restrict__ out) {
    const int m = blockIdx.x, tid = threadIdx.x;
    u32 cnt = ws->ecnt[m];
    if (cnt > (u32)N) cnt = (u32)N;
    float acc = 0.f;
    for (u32 i = (u32)tid; i < cnt; i += 256u) {
        u32 pk = ws->edges[m][i];
        u32 lo = (pk >> 12) & 0xFFFu, hi = pk & 0xFFFu;
        size_t off = (size_t)lo * N + hi;
        float df = d1[off] - d2[off];
        acc += df * df;
    }
    #pragma unroll
    for (int off = 32; off >= 1; off >>= 1) acc += __shfl_down(acc, off, 64);
    __shared__ float part[4];
    const int lane = tid & 63, wave = tid >> 6;
    if (lane == 0) part[wave] = acc;
    __syncthreads();
    if (tid == 0) atomicAdd(out, part[0] + part[1] + part[2] + part[3]);
}

extern "C" void kernel_launch(void* const* d_in, const int* in_sizes, int n_in,
                              void* d_out, int out_size, void* d_ws, size_t ws_size,
                              hipStream_t stream) {
    (void)in_sizes; (void)n_in; (void)out_size; (void)ws_size;
    const float* d1 = (const float*)d_in[0];
    const float* d2 = (const float*)d_in[1];
    float* out = (float*)d_out;
    Ws* ws = (Ws*)d_ws;   // ~160 KB of scratch

    hipMemsetAsync(d_out, 0, sizeof(float), stream);
    init_k<<<dim3(16), dim3(256), 0, stream>>>(ws);
    for (int r = 0; r < NROUNDS; ++r) {
        scan_k<<<dim3(2048), dim3(256), 0, stream>>>(d1, d2, ws, r == 0 ? 1 : 0);
        hook_k<<<dim3(2), dim3(256), 0, stream>>>(ws);
    }
    epi_k<<<dim3(2), dim3(256), 0, stream>>>(d1, d2, ws, out);
}

// Round 5
// 314.924 us; speedup vs baseline: 1.3768x; 1.1378x over previous
//
#include <hip/hip_runtime.h>
#include <stdint.h>

// TopoSignature via parallel Boruvka MST. Round 5: hook_k atomic-free edge
// recording (slot = dying root id; diagonal sentinel contributes exactly 0
// in the epilogue) + 1024-thread hook (4 slots/thread, 16 waves) to cut
// latency chains. scan_k unchanged from round 4 (one wave/row, batched MLP).

#define N        4096
#define NROUNDS  12

typedef unsigned long long u64;
typedef uint32_t u32;

struct Ws {
    u64 best[2][N];     // per-component min outgoing edge key: (wbits<<24)|(lo<<12)|hi
    u32 comp[2][N];     // vertex -> component root label
    u32 edges[2][N];    // edge slot per vertex, (lo<<12)|hi; (i<<12)|i = none
    u32 ncomp[2];
};

__device__ __forceinline__ u64 shfl_down_u64(u64 x, int off) {
    u32 lo = (u32)x, hi = (u32)(x >> 32);
    lo = (u32)__shfl_down((int)lo, off, 64);
    hi = (u32)__shfl_down((int)hi, off, 64);
    return ((u64)hi << 32) | lo;
}

__global__ void init_k(Ws* __restrict__ ws) {
    int i = blockIdx.x * blockDim.x + threadIdx.x;
    if (i < N) {
        ws->best[0][i] = ~0ull; ws->best[1][i] = ~0ull;
        ws->comp[0][i] = (u32)i; ws->comp[1][i] = (u32)i;
        u32 diag = ((u32)i << 12) | (u32)i;
        ws->edges[0][i] = diag; ws->edges[1][i] = diag;
        if (i < 2) ws->ncomp[i] = (u32)N;
    }
}

// One wave per row. Blocks 0..1023: matrix 0; 1024..2047: matrix 1.
__launch_bounds__(256, 8)
__global__ void scan_k(const float* __restrict__ d1, const float* __restrict__ d2,
                       Ws* __restrict__ ws, int first) {
    const int m = blockIdx.x >> 10;
    if (ws->ncomp[m] <= 1u) return;              // uniform per block
    const int wave = threadIdx.x >> 6, lane = threadIdx.x & 63;
    const int v = ((blockIdx.x & 1023) << 2) + wave;

    const float* __restrict__ dm = m ? d2 : d1;
    const u32*   __restrict__ cm = ws->comp[m];
    const float4* __restrict__ row4 = (const float4*)(dm + (size_t)v * N);
    const uint4*  __restrict__ c4   = (const uint4*)cm;
    const u32 cv = first ? (u32)v : cm[v];

    float wmin = __int_as_float(0x7F800000);     // +inf
    u32   colmin = 0u;

    #pragma unroll
    for (int bb = 0; bb < 4; ++bb) {
        float4 w[4];
        uint4  cu[4];
        #pragma unroll
        for (int i = 0; i < 4; ++i) {
            const int c = lane + 64 * (bb * 4 + i);
            w[i] = row4[c];
            if (!first) cu[i] = c4[c];
        }
        #pragma unroll
        for (int i = 0; i < 4; ++i) {
            const u32 c0 = (u32)(4 * (lane + 64 * (bb * 4 + i)));
            if (first) {
                const u32 uv = (u32)v;
                if (c0+0 != uv && w[i].x < wmin) { wmin = w[i].x; colmin = c0+0; }
                if (c0+1 != uv && w[i].y < wmin) { wmin = w[i].y; colmin = c0+1; }
                if (c0+2 != uv && w[i].z < wmin) { wmin = w[i].z; colmin = c0+2; }
                if (c0+3 != uv && w[i].w < wmin) { wmin = w[i].w; colmin = c0+3; }
            } else {
                if (cu[i].x != cv && w[i].x < wmin) { wmin = w[i].x; colmin = c0+0; }
                if (cu[i].y != cv && w[i].y < wmin) { wmin = w[i].y; colmin = c0+1; }
                if (cu[i].z != cv && w[i].z < wmin) { wmin = w[i].z; colmin = c0+2; }
                if (cu[i].w != cv && w[i].w < wmin) { wmin = w[i].w; colmin = c0+3; }
            }
        }
    }

    u64 kmin = ((u64)__float_as_uint(wmin) << 32) | (u64)colmin;
    #pragma unroll
    for (int off = 32; off >= 1; off >>= 1) {
        u64 o = shfl_down_u64(kmin, off);
        if (o < kmin) kmin = o;
    }
    if (lane == 0) {
        u32 wb = (u32)(kmin >> 32);
        u32 u  = (u32)kmin & 0xFFFu;
        u32 lo = min((u32)v, u), hi = max((u32)v, u);
        u64 g  = ((u64)wb << 24) | ((u64)lo << 12) | (u64)hi;
        if (first) {
            ws->best[m][v] = g;                  // comp==v, unique -> plain store
        } else {
            if (g < ws->best[m][cv])             // read-check kills atomic serialization
                atomicMin(&ws->best[m][cv], g);
        }
    }
}

// Hook roots along min edges, resolve 2-cycles, record edges (slot-per-root,
// no atomics), pointer-jump, relabel comp, reset best, update ncomp.
// One 1024-thread block per matrix; 4 slots per thread.
__launch_bounds__(1024, 1)
__global__ void hook_k(Ws* __restrict__ ws) {
    const int m = blockIdx.x;
    const int tid = threadIdx.x;
    if (ws->ncomp[m] <= 1u) return;

    u32* __restrict__ gcomp = ws->comp[m];
    u64* __restrict__ best  = ws->best[m];

    __shared__ u32 compL[N];
    __shared__ u32 nxtA[N];
    __shared__ u32 nxtB[N];
    __shared__ u32 red[16];

    {
        uint4* dst = (uint4*)compL;
        const uint4* src = (const uint4*)gcomp;
        if (tid < N / 4) dst[tid] = src[tid];
    }
    __syncthreads();

    bool isroot[4];
    u64  bkey[4];

    // A: each root hooks toward the other endpoint's component
    #pragma unroll
    for (int k = 0; k < 4; ++k) {
        int i = tid + k * 1024;
        u32 x = (u32)i;
        bool r = (compL[i] == (u32)i);
        isroot[k] = r;
        u64 g = 0;
        if (r) {
            g = best[i];
            u32 lo = (u32)(g >> 12) & 0xFFFu;
            u32 hi = (u32)g & 0xFFFu;
            u32 cl = compL[lo], ch = compL[hi];
            x = (cl == (u32)i) ? ch : cl;
        }
        bkey[k] = g;
        nxtA[i] = x;
    }
    __syncthreads();

    // B: only 2-cycles possible (strict total order); smaller id stays root.
    // A root that dies records its edge at slot = its own id (once per run).
    #pragma unroll
    for (int k = 0; k < 4; ++k) {
        int i = tid + k * 1024;
        u32 nn = (u32)i;
        if (isroot[k]) {
            u32 o = nxtA[i];
            bool mutual = (nxtA[o] == (u32)i);
            nn = (mutual && ((u32)i < o)) ? (u32)i : o;
            if (nn != (u32)i)
                ws->edges[m][i] = (u32)(bkey[k] & 0xFFFFFFu);
        }
        nxtB[i] = nn;
    }
    __syncthreads();

    // C: pointer jumping (12 steps covers any depth <= 4096)
    for (int s = 0; s < 12; ++s) {
        #pragma unroll
        for (int k = 0; k < 4; ++k) {
            int i = tid + k * 1024;
            nxtB[i] = nxtB[nxtB[i]];
        }
        __syncthreads();
    }

    // D: count surviving roots (among OLD roots)
    u32 cnt = 0;
    #pragma unroll
    for (int k = 0; k < 4; ++k) {
        int i = tid + k * 1024;
        if (isroot[k] && nxtB[i] == (u32)i) cnt++;
    }
    #pragma unroll
    for (int off = 32; off >= 1; off >>= 1) cnt += (u32)__shfl_down((int)cnt, off, 64);
    const int lane = tid & 63, wave = tid >> 6;
    if (lane == 0) red[wave] = cnt;
    __syncthreads();

    // E: relabel comp (global), reset best cells of old roots
    #pragma unroll
    for (int k = 0; k < 4; ++k) {
        int i = tid + k * 1024;
        gcomp[i] = nxtB[compL[i]];
        if (isroot[k]) best[i] = ~0ull;
    }
    if (tid == 0) {
        u32 t = 0;
        #pragma unroll
        for (int w = 0; w < 16; ++w) t += red[w];
        ws->ncomp[m] = t;
    }
}

__launch_bounds__(256, 1)
__global__ void epi_k(const float* __restrict__ d1, const float* __restrict__ d2,
                      Ws* __restrict__ ws, float* __restrict__ out) {
    const int m = blockIdx.x, tid = threadIdx.x;
    float acc = 0.f;
    for (int i = tid; i < N; i += 256) {
        u32 pk = ws->edges[m][i];
        u32 lo = (pk >> 12) & 0xFFFu, hi = pk & 0xFFFu;
        size_t off = (size_t)lo * N + hi;
        float df = d1[off] - d2[off];     // diagonal sentinel -> 0-0 = 0
        acc += df * df;
    }
    #pragma unroll
    for (int off = 32; off >= 1; off >>= 1) acc += __shfl_down(acc, off, 64);
    __shared__ float part[4];
    const int lane = tid & 63, wave = tid >> 6;
    if (lane == 0) part[wave] = acc;
    __syncthreads();
    if (tid == 0) atomicAdd(out, part[0] + part[1] + part[2] + part[3]);
}

extern "C" void kernel_launch(void* const* d_in, const int* in_sizes, int n_in,
                              void* d_out, int out_size, void* d_ws, size_t ws_size,
                              hipStream_t stream) {
    (void)in_sizes; (void)n_in; (void)out_size; (void)ws_size;
    const float* d1 = (const float*)d_in[0];
    const float* d2 = (const float*)d_in[1];
    float* out = (float*)d_out;
    Ws* ws = (Ws*)d_ws;   // ~112 KB of scratch

    hipMemsetAsync(d_out, 0, sizeof(float), stream);
    init_k<<<dim3(16), dim3(256), 0, stream>>>(ws);
    for (int r = 0; r < NROUNDS; ++r) {
        scan_k<<<dim3(2048), dim3(256), 0, stream>>>(d1, d2, ws, r == 0 ? 1 : 0);
        hook_k<<<dim3(2), dim3(1024), 0, stream>>>(ws);
    }
    epi_k<<<dim3(2), dim3(256), 0, stream>>>(d1, d2, ws, out);
}

// Round 6
// 280.968 us; speedup vs baseline: 1.5431x; 1.1209x over previous
//
#include <hip/hip_runtime.h>
#include <stdint.h>

// TopoSignature via parallel Boruvka MST. Round 6: block-min bound table.
// Round 1 full scan also emits per-row per-64-col-block min keys (4 MB).
// Later rounds read 512 B/row of bounds; only blocks whose stored intra
// bound undercuts the best cross candidate are rescanned (256 B each),
// and the slot is tightened to the block's min-cross key. Exact.

#define N        4096
#define NROUNDS  12

typedef unsigned long long u64;
typedef uint32_t u32;

#define INFK (~0ull)

struct Ws {
    u64 best[2][N];      // per-component min outgoing edge key: (wbits<<24)|(lo<<12)|hi
    u32 comp[2][N];      // vertex -> component root label
    u32 edges[2][N];     // edge slot per vertex, (lo<<12)|hi; (i<<12)|i = none
    u32 ncomp[2];
    u32 pad[14];
    u64 bm[2][N * 64];   // per-row per-block bound keys: (wbits<<12)|col ; 4 MB
};

__device__ __forceinline__ u64 umin64(u64 a, u64 b) { return a < b ? a : b; }

__device__ __forceinline__ u64 shfl_down_u64(u64 x, int off) {
    u32 lo = (u32)x, hi = (u32)(x >> 32);
    lo = (u32)__shfl_down((int)lo, off, 64);
    hi = (u32)__shfl_down((int)hi, off, 64);
    return ((u64)hi << 32) | lo;
}
__device__ __forceinline__ u64 shfl_xor_u64(u64 x, int off) {
    u32 lo = (u32)x, hi = (u32)(x >> 32);
    lo = (u32)__shfl_xor((int)lo, off, 64);
    hi = (u32)__shfl_xor((int)hi, off, 64);
    return ((u64)hi << 32) | lo;
}

__global__ void init_k(Ws* __restrict__ ws) {
    int i = blockIdx.x * blockDim.x + threadIdx.x;
    if (i < N) {
        ws->best[0][i] = INFK; ws->best[1][i] = INFK;
        ws->comp[0][i] = (u32)i; ws->comp[1][i] = (u32)i;
        u32 diag = ((u32)i << 12) | (u32)i;
        ws->edges[0][i] = diag; ws->edges[1][i] = diag;
        if (i < 2) ws->ncomp[i] = (u32)N;
    }
}

// Round 1: full scan, one wave per row; also build block-min table.
// Block b = cols [64b, 64b+64). At iter i, 16-lane group g holds block 4i+g.
__launch_bounds__(256, 8)
__global__ void scanA_k(const float* __restrict__ d1, const float* __restrict__ d2,
                        Ws* __restrict__ ws) {
    const int m = blockIdx.x >> 10;
    const int wave = threadIdx.x >> 6, lane = threadIdx.x & 63;
    const int v = ((blockIdx.x & 1023) << 2) + wave;
    const float4* __restrict__ row4 = (const float4*)((m ? d2 : d1) + (size_t)v * N);
    u64* __restrict__ bmrow = ws->bm[m] + (size_t)v * 64;

    __shared__ u64 bs[4][64];

    const u32 uv = (u32)v;
    u64 rowmin = INFK;

    #pragma unroll
    for (int i = 0; i < 16; ++i) {
        const int c = lane + 64 * i;
        float4 w = row4[c];
        const u32 c0 = (u32)(4 * c);
        u64 k0 = (c0 + 0 == uv) ? INFK : ((((u64)__float_as_uint(w.x)) << 12) | (c0 + 0));
        u64 k1 = (c0 + 1 == uv) ? INFK : ((((u64)__float_as_uint(w.y)) << 12) | (c0 + 1));
        u64 k2 = (c0 + 2 == uv) ? INFK : ((((u64)__float_as_uint(w.z)) << 12) | (c0 + 2));
        u64 k3 = (c0 + 3 == uv) ? INFK : ((((u64)__float_as_uint(w.w)) << 12) | (c0 + 3));
        u64 kk = umin64(umin64(k0, k1), umin64(k2, k3));
        // 16-lane butterfly -> every lane of the group holds the block min
        #pragma unroll
        for (int off = 1; off <= 8; off <<= 1)
            kk = umin64(kk, shfl_xor_u64(kk, off));
        if ((lane & 15) == 0) bs[wave][4 * i + (lane >> 4)] = kk;
        rowmin = umin64(rowmin, kk);
    }
    // combine the 4 groups -> full row min on every lane
    rowmin = umin64(rowmin, shfl_xor_u64(rowmin, 16));
    rowmin = umin64(rowmin, shfl_xor_u64(rowmin, 32));

    __syncthreads();
    bmrow[lane] = bs[wave][lane];                 // coalesced 512 B store

    if (lane == 0) {
        u32 wb = (u32)(rowmin >> 12);
        u32 u  = (u32)rowmin & 0xFFFu;
        u32 lo = min(uv, u), hi = max(uv, u);
        ws->best[m][v] = ((u64)wb << 24) | ((u64)lo << 12) | (u64)hi;  // comp==v
    }
}

// Rounds 2+: bound-table scan. One wave per row, lane = block.
__launch_bounds__(256, 8)
__global__ void scan2_k(const float* __restrict__ d1, const float* __restrict__ d2,
                        Ws* __restrict__ ws) {
    const int m = blockIdx.x >> 10;
    if (ws->ncomp[m] <= 1u) return;
    const int wave = threadIdx.x >> 6, lane = threadIdx.x & 63;
    const int v = ((blockIdx.x & 1023) << 2) + wave;

    const float* __restrict__ dm = m ? d2 : d1;
    const u32*   __restrict__ cm = ws->comp[m];
    u64* __restrict__ bmrow = ws->bm[m] + (size_t)v * 64;

    const u32 cv = cm[v];
    u64 key = bmrow[lane];
    bool cross = false;
    if (key != INFK) cross = (cm[(u32)key & 0xFFFu] != cv);

    // best cross candidate among stored block mins (exact entries)
    u64 kb = cross ? key : INFK;
    #pragma unroll
    for (int off = 1; off <= 32; off <<= 1)
        kb = umin64(kb, shfl_xor_u64(kb, off));

    // intra bound undercutting kb -> block may hide a smaller cross entry
    const bool need = (!cross) && (key < kb);
    u64 nm = INFK;
    if (need) {
        const float4* __restrict__ row4 = (const float4*)(dm + (size_t)v * N);
        const uint4*  __restrict__ c4   = (const uint4*)cm;
        #pragma unroll
        for (int j = 0; j < 16; ++j) {
            float4 w = row4[lane * 16 + j];
            uint4 cu = c4[lane * 16 + j];
            u32 c0 = (u32)(4 * (lane * 16 + j));
            if (cu.x != cv) nm = umin64(nm, (((u64)__float_as_uint(w.x)) << 12) | (c0 + 0));
            if (cu.y != cv) nm = umin64(nm, (((u64)__float_as_uint(w.y)) << 12) | (c0 + 1));
            if (cu.z != cv) nm = umin64(nm, (((u64)__float_as_uint(w.z)) << 12) | (c0 + 2));
            if (cu.w != cv) nm = umin64(nm, (((u64)__float_as_uint(w.w)) << 12) | (c0 + 3));
        }
        bmrow[lane] = nm;    // tightened bound: block's current min-cross key
    }
    u64 kb2 = need ? nm : INFK;
    #pragma unroll
    for (int off = 1; off <= 32; off <<= 1)
        kb2 = umin64(kb2, shfl_xor_u64(kb2, off));

    u64 fin = umin64(kb, kb2);
    if (lane == 0 && fin != INFK) {
        u32 wb = (u32)(fin >> 12);
        u32 u  = (u32)fin & 0xFFFu;
        u32 lo = min((u32)v, u), hi = max((u32)v, u);
        u64 g  = ((u64)wb << 24) | ((u64)lo << 12) | (u64)hi;
        if (g < ws->best[m][cv])
            atomicMin(&ws->best[m][cv], g);
    }
}

// Fallback full scan (used when ws_size too small for the bound table).
__launch_bounds__(256, 8)
__global__ void scanF_k(const float* __restrict__ d1, const float* __restrict__ d2,
                        Ws* __restrict__ ws, int first) {
    const int m = blockIdx.x >> 10;
    if (ws->ncomp[m] <= 1u) return;
    const int wave = threadIdx.x >> 6, lane = threadIdx.x & 63;
    const int v = ((blockIdx.x & 1023) << 2) + wave;
    const float* __restrict__ dm = m ? d2 : d1;
    const u32*   __restrict__ cm = ws->comp[m];
    const float4* __restrict__ row4 = (const float4*)(dm + (size_t)v * N);
    const uint4*  __restrict__ c4   = (const uint4*)cm;
    const u32 cv = first ? (u32)v : cm[v];
    float wmin = __int_as_float(0x7F800000);
    u32 colmin = 0u;
    #pragma unroll
    for (int bb = 0; bb < 4; ++bb) {
        float4 w[4]; uint4 cu[4];
        #pragma unroll
        for (int i = 0; i < 4; ++i) {
            const int c = lane + 64 * (bb * 4 + i);
            w[i] = row4[c];
            if (!first) cu[i] = c4[c];
        }
        #pragma unroll
        for (int i = 0; i < 4; ++i) {
            const u32 c0 = (u32)(4 * (lane + 64 * (bb * 4 + i)));
            if (first) {
                const u32 uv = (u32)v;
                if (c0+0 != uv && w[i].x < wmin) { wmin = w[i].x; colmin = c0+0; }
                if (c0+1 != uv && w[i].y < wmin) { wmin = w[i].y; colmin = c0+1; }
                if (c0+2 != uv && w[i].z < wmin) { wmin = w[i].z; colmin = c0+2; }
                if (c0+3 != uv && w[i].w < wmin) { wmin = w[i].w; colmin = c0+3; }
            } else {
                if (cu[i].x != cv && w[i].x < wmin) { wmin = w[i].x; colmin = c0+0; }
                if (cu[i].y != cv && w[i].y < wmin) { wmin = w[i].y; colmin = c0+1; }
                if (cu[i].z != cv && w[i].z < wmin) { wmin = w[i].z; colmin = c0+2; }
                if (cu[i].w != cv && w[i].w < wmin) { wmin = w[i].w; colmin = c0+3; }
            }
        }
    }
    u64 kmin = ((u64)__float_as_uint(wmin) << 32) | (u64)colmin;
    #pragma unroll
    for (int off = 32; off >= 1; off >>= 1)
        kmin = umin64(kmin, shfl_down_u64(kmin, off));
    if (lane == 0) {
        u32 wb = (u32)(kmin >> 32);
        u32 u  = (u32)kmin & 0xFFFu;
        u32 lo = min((u32)v, u), hi = max((u32)v, u);
        u64 g  = ((u64)wb << 24) | ((u64)lo << 12) | (u64)hi;
        if (first) ws->best[m][v] = g;
        else if (g < ws->best[m][cv]) atomicMin(&ws->best[m][cv], g);
    }
}

// Hook roots, resolve 2-cycles, record edges (slot = dying root id),
// pointer-jump, relabel, reset best. One 1024-thread block per matrix.
__launch_bounds__(1024, 1)
__global__ void hook_k(Ws* __restrict__ ws) {
    const int m = blockIdx.x;
    const int tid = threadIdx.x;
    if (ws->ncomp[m] <= 1u) return;

    u32* __restrict__ gcomp = ws->comp[m];
    u64* __restrict__ best  = ws->best[m];

    __shared__ u32 compL[N];
    __shared__ u32 nxtA[N];
    __shared__ u32 nxtB[N];
    __shared__ u32 red[16];

    {
        uint4* dst = (uint4*)compL;
        const uint4* src = (const uint4*)gcomp;
        if (tid < N / 4) dst[tid] = src[tid];
    }
    __syncthreads();

    bool isroot[4];
    u64  bkey[4];

    #pragma unroll
    for (int k = 0; k < 4; ++k) {
        int i = tid + k * 1024;
        u32 x = (u32)i;
        bool r = (compL[i] == (u32)i);
        isroot[k] = r;
        u64 g = 0;
        if (r) {
            g = best[i];
            u32 lo = (u32)(g >> 12) & 0xFFFu;
            u32 hi = (u32)g & 0xFFFu;
            u32 cl = compL[lo], ch = compL[hi];
            x = (cl == (u32)i) ? ch : cl;
        }
        bkey[k] = g;
        nxtA[i] = x;
    }
    __syncthreads();

    #pragma unroll
    for (int k = 0; k < 4; ++k) {
        int i = tid + k * 1024;
        u32 nn = (u32)i;
        if (isroot[k]) {
            u32 o = nxtA[i];
            bool mutual = (nxtA[o] == (u32)i);
            nn = (mutual && ((u32)i < o)) ? (u32)i : o;
            if (nn != (u32)i)
                ws->edges[m][i] = (u32)(bkey[k] & 0xFFFFFFu);
        }
        nxtB[i] = nn;
    }
    __syncthreads();

    for (int s = 0; s < 12; ++s) {
        #pragma unroll
        for (int k = 0; k < 4; ++k) {
            int i = tid + k * 1024;
            nxtB[i] = nxtB[nxtB[i]];
        }
        __syncthreads();
    }

    u32 cnt = 0;
    #pragma unroll
    for (int k = 0; k < 4; ++k) {
        int i = tid + k * 1024;
        if (isroot[k] && nxtB[i] == (u32)i) cnt++;
    }
    #pragma unroll
    for (int off = 32; off >= 1; off >>= 1) cnt += (u32)__shfl_down((int)cnt, off, 64);
    const int lane = tid & 63, wave = tid >> 6;
    if (lane == 0) red[wave] = cnt;
    __syncthreads();

    #pragma unroll
    for (int k = 0; k < 4; ++k) {
        int i = tid + k * 1024;
        gcomp[i] = nxtB[compL[i]];
        if (isroot[k]) best[i] = INFK;
    }
    if (tid == 0) {
        u32 t = 0;
        #pragma unroll
        for (int w = 0; w < 16; ++w) t += red[w];
        ws->ncomp[m] = t;
    }
}

__launch_bounds__(256, 1)
__global__ void epi_k(const float* __restrict__ d1, const float* __restrict__ d2,
                      Ws* __restrict__ ws, float* __restrict__ out) {
    const int m = blockIdx.x, tid = threadIdx.x;
    float acc = 0.f;
    for (int i = tid; i < N; i += 256) {
        u32 pk = ws->edges[m][i];
        u32 lo = (pk >> 12) & 0xFFFu, hi = pk & 0xFFFu;
        size_t off = (size_t)lo * N + hi;
        float df = d1[off] - d2[off];     // diagonal sentinel -> 0
        acc += df * df;
    }
    #pragma unroll
    for (int off = 32; off >= 1; off >>= 1) acc += __shfl_down(acc, off, 64);
    __shared__ float part[4];
    const int lane = tid & 63, wave = tid >> 6;
    if (lane == 0) part[wave] = acc;
    __syncthreads();
    if (tid == 0) atomicAdd(out, part[0] + part[1] + part[2] + part[3]);
}

extern "C" void kernel_launch(void* const* d_in, const int* in_sizes, int n_in,
                              void* d_out, int out_size, void* d_ws, size_t ws_size,
                              hipStream_t stream) {
    (void)in_sizes; (void)n_in; (void)out_size;
    const float* d1 = (const float*)d_in[0];
    const float* d2 = (const float*)d_in[1];
    float* out = (float*)d_out;
    Ws* ws = (Ws*)d_ws;
    const bool big = (ws_size >= sizeof(Ws));   // ~4.4 MB needed for bound table

    hipMemsetAsync(d_out, 0, sizeof(float), stream);
    init_k<<<dim3(16), dim3(256), 0, stream>>>(ws);
    for (int r = 0; r < NROUNDS; ++r) {
        if (big) {
            if (r == 0) scanA_k<<<dim3(2048), dim3(256), 0, stream>>>(d1, d2, ws);
            else        scan2_k<<<dim3(2048), dim3(256), 0, stream>>>(d1, d2, ws);
        } else {
            scanF_k<<<dim3(2048), dim3(256), 0, stream>>>(d1, d2, ws, r == 0 ? 1 : 0);
        }
        hook_k<<<dim3(2), dim3(1024), 0, stream>>>(ws);
    }
    epi_k<<<dim3(2), dim3(256), 0, stream>>>(d1, d2, ws, out);
}